// Round 8
// baseline (391.801 us; speedup 1.0000x reference)
//
#include <hip/hip_runtime.h>
#include <hip/hip_cooperative_groups.h>

namespace cg = cooperative_groups;

typedef unsigned short u16;
typedef __attribute__((ext_vector_type(8))) short short8;
typedef __attribute__((ext_vector_type(4))) float f32x4;

// ---------- helpers ----------

__device__ __forceinline__ u16 f2bf(float f) {
  unsigned u = __builtin_bit_cast(unsigned, f);
  u += 0x7fffu + ((u >> 16) & 1u);   // RNE
  return (u16)(u >> 16);
}

__device__ __forceinline__ void gload16(const void* g, void* l) {
  __builtin_amdgcn_global_load_lds(
      (const __attribute__((address_space(1))) unsigned*)g,
      (__attribute__((address_space(3))) unsigned*)l, 16, 0, 0);
}

#define MFMA16(a, b, c) __builtin_amdgcn_mfma_f32_16x16x32_bf16(a, b, c, 0, 0, 0)

// ================================================================
// Round-3 proven 256x128 GEMM core: BK=64, 3 LDS buffers, dist-2
// prefetch, counted vmcnt(6), ONE barrier per K-tile.
// ================================================================

#define PTILE(RB_C, RB_N, DOSTAGE, VM, LAST)                                  \
  {                                                                           \
    char* cA = sA0 + cur * 49152;                                             \
    /* ---- phase 0 ---- */                                                   \
    if (DOSTAGE) {                                                            \
      const int ns = (cur + 2 >= 3) ? cur - 1 : cur + 2;                      \
      char* dA = sA0 + ns * 49152;                                            \
      _Pragma("unroll") for (int j = 0; j < 3; ++j) {                         \
        gload16(ga[j], dA + la[j]); ga[j] += 64; }                            \
    }                                                                         \
    _Pragma("unroll") for (int kk = 0; kk < 2; ++kk)                          \
      _Pragma("unroll") for (int i = 0; i < 2; ++i) {                         \
        const int rm = wr + 32 + i * 16 + l16;                                \
        a1f[kk][i] = *(const short8*)(cA + rm * 128 +                         \
            (((kk << 2) + quad) ^ (rm & 7)) * 16);                            \
      }                                                                       \
    asm volatile("s_waitcnt lgkmcnt(4)" ::: "memory");                        \
    __builtin_amdgcn_sched_barrier(0);                                        \
    __builtin_amdgcn_s_setprio(1);                                            \
    _Pragma("unroll") for (int kk = 0; kk < 2; ++kk)                          \
      _Pragma("unroll") for (int i = 0; i < 2; ++i)                           \
        _Pragma("unroll") for (int j = 0; j < 4; ++j)                         \
          acc[i][j] = MFMA16(a0f[kk][i], RB_C[kk][j], acc[i][j]);             \
    __builtin_amdgcn_s_setprio(0);                                            \
    /* ---- phase 1 ---- */                                                   \
    if (DOSTAGE) {                                                            \
      const int ns = (cur + 2 >= 3) ? cur - 1 : cur + 2;                      \
      char* dA = sA0 + ns * 49152; char* dB = dA + 32768;                     \
      gload16(ga[3], dA + la[3]); ga[3] += 64;                                \
      _Pragma("unroll") for (int j = 0; j < 2; ++j) {                         \
        gload16(gb[j], dB + lb[j]); gb[j] += 64; }                            \
    }                                                                         \
    if (!(LAST)) {                                                            \
      asm volatile("s_waitcnt vmcnt(" #VM ") lgkmcnt(0)" ::: "memory");       \
      __builtin_amdgcn_s_barrier();                                           \
      asm volatile("" ::: "memory");                                          \
      const int nc = (cur + 1 >= 3) ? 0 : cur + 1;                            \
      char* nA = sA0 + nc * 49152; char* nB = nA + 32768;                     \
      _Pragma("unroll") for (int kk = 0; kk < 2; ++kk)                        \
        _Pragma("unroll") for (int j = 0; j < 4; ++j) {                       \
          const int rn = wc + j * 16 + l16;                                   \
          RB_N[kk][j] = *(const short8*)(nB + rn * 128 +                      \
              (((kk << 2) + quad) ^ (rn & 7)) * 16);                          \
        }                                                                     \
      _Pragma("unroll") for (int kk = 0; kk < 2; ++kk)                        \
        _Pragma("unroll") for (int i = 0; i < 2; ++i) {                       \
          const int rm = wr + i * 16 + l16;                                   \
          a0f[kk][i] = *(const short8*)(nA + rm * 128 +                       \
              (((kk << 2) + quad) ^ (rm & 7)) * 16);                          \
        }                                                                     \
    } else {                                                                  \
      asm volatile("s_waitcnt lgkmcnt(0)" ::: "memory");                      \
    }                                                                         \
    __builtin_amdgcn_sched_barrier(0);                                        \
    __builtin_amdgcn_s_setprio(1);                                            \
    _Pragma("unroll") for (int kk = 0; kk < 2; ++kk)                          \
      _Pragma("unroll") for (int i = 0; i < 2; ++i)                           \
        _Pragma("unroll") for (int j = 0; j < 4; ++j)                         \
          acc[2 + i][j] = MFMA16(a1f[kk][i], RB_C[kk][j], acc[2 + i][j]);     \
    __builtin_amdgcn_s_setprio(0);                                            \
    cur = (cur + 1 >= 3) ? 0 : cur + 1;                                       \
  }

__device__ __forceinline__ void gemm_256x128(
    const u16* __restrict__ A, const u16* __restrict__ B,
    int m0, int n0, int ntiles, char* smem, f32x4 acc[4][4])
{
  const int tid  = threadIdx.x;          // 0..511
  const int lane = tid & 63;
  const int quad = lane >> 4;
  const int l16  = lane & 15;
  const int wave = tid >> 6;             // 0..7
  const int wr   = (wave >> 1) << 6;     // 0,64,128,192
  const int wc   = (wave & 1) << 6;      // 0,64

  const u16* ga[4]; int la[4];
  const u16* gb[2]; int lb[2];
#pragma unroll
  for (int j = 0; j < 4; ++j) {
    const int L = j * 512 + tid;         // 2048 chunks: 256 rows x 8
    const int r = L >> 3;
    const int c = (L & 7) ^ (r & 7);
    la[j] = L * 16;
    ga[j] = A + (size_t)(m0 + r) * 1024 + c * 8;
  }
#pragma unroll
  for (int j = 0; j < 2; ++j) {
    const int L = j * 512 + tid;         // 1024 chunks: 128 rows x 8
    const int r = L >> 3;
    const int c = (L & 7) ^ (r & 7);
    lb[j] = L * 16;
    gb[j] = B + (size_t)(n0 + r) * 1024 + c * 8;
  }
  char* const sA0 = smem;                // buf b: A at b*49152, B at +32768

  short8 bfr0[2][4], bfr1[2][4];         // B frags, double-buffered
  short8 a0f[2][2], a1f[2][2];           // A frags rows 0..31 / 32..63

  // prologue: stage tiles 0 and 1 (6 gloads each)
  {
    char* dA = sA0; char* dB = sA0 + 32768;
#pragma unroll
    for (int j = 0; j < 4; ++j) { gload16(ga[j], dA + la[j]); ga[j] += 64; }
#pragma unroll
    for (int j = 0; j < 2; ++j) { gload16(gb[j], dB + lb[j]); gb[j] += 64; }
    dA = sA0 + 49152; dB = dA + 32768;
#pragma unroll
    for (int j = 0; j < 4; ++j) { gload16(ga[j], dA + la[j]); ga[j] += 64; }
#pragma unroll
    for (int j = 0; j < 2; ++j) { gload16(gb[j], dB + lb[j]); gb[j] += 64; }
  }
  asm volatile("s_waitcnt vmcnt(6)" ::: "memory");   // tile0 done, tile1 in flight
  __builtin_amdgcn_s_barrier();
  asm volatile("" ::: "memory");
  {
    char* nA = sA0; char* nB = sA0 + 32768;
#pragma unroll
    for (int kk = 0; kk < 2; ++kk)
#pragma unroll
      for (int j = 0; j < 4; ++j) {
        const int rn = wc + j * 16 + l16;
        bfr0[kk][j] = *(const short8*)(nB + rn * 128 + (((kk << 2) + quad) ^ (rn & 7)) * 16);
      }
#pragma unroll
    for (int kk = 0; kk < 2; ++kk)
#pragma unroll
      for (int i = 0; i < 2; ++i) {
        const int rm = wr + i * 16 + l16;
        a0f[kk][i] = *(const short8*)(nA + rm * 128 + (((kk << 2) + quad) ^ (rm & 7)) * 16);
      }
  }

  int cur = 0;
  const int npair = (ntiles >> 1) - 1;
#pragma unroll 1
  for (int it = 0; it < npair; ++it) {
    PTILE(bfr0, bfr1, true, 6, false);
    PTILE(bfr1, bfr0, true, 6, false);
  }
  PTILE(bfr0, bfr1, false, 0, false);
  PTILE(bfr1, bfr0, false, 0, true);
  __syncthreads();                       // epilogue may rewrite LDS
}

#define ACC_ZERO4(acc) { _Pragma("unroll") for (int i=0;i<4;++i) \
  _Pragma("unroll") for (int j=0;j<4;++j) \
  _Pragma("unroll") for (int r=0;r<4;++r) acc[i][j][r]=0.f; }

// ---------- epilogue: 256x128 acc(+bias) -> bf16 C via LDS repack ----------
__device__ __forceinline__ void store256x128_bf16(
    f32x4 acc[4][4], const float* bias, int n0,
    u16* C, int m0, char* smem)
{
  const int tid = threadIdx.x, lane = tid & 63, wave = tid >> 6;
  const int quad = lane >> 4, l16 = lane & 15;
  const int wr = (wave >> 1) << 6, wc = (wave & 1) << 6;
  u16* t = (u16*)smem;                       // 256 x 136 u16
#pragma unroll
  for (int j = 0; j < 4; ++j) {
    const int nn = wc + j * 16 + l16;
    const float bj = bias[n0 + nn];
#pragma unroll
    for (int i = 0; i < 4; ++i) {
      const int mm = wr + i * 16 + quad * 4;
#pragma unroll
      for (int r = 0; r < 4; ++r)
        t[(mm + r) * 136 + nn] = f2bf(acc[i][j][r] + bj);
    }
  }
  __syncthreads();
#pragma unroll
  for (int it = 0; it < 8; ++it) {
    const int L = it * 512 + tid;              // 4096 chunks of 8 u16
    const int mm = L >> 4, cc = L & 15;
    *(uint4*)(C + (size_t)(m0 + mm) * 1024 + n0 + cc * 8) =
        *(const uint4*)(t + mm * 136 + cc * 8);
  }
}

// ================================================================
// ONE cooperative kernel: 256 blocks x 512 threads, 1 block/CU,
// phases separated by grid.sync() (replaces 4 kernel boundaries).
//   P0 cast -> P1 proj QKV (z-loop, x L2-resident) -> P2 qk_exp
//   -> P3 pv -> P4 proj_o
// ================================================================
__global__ __launch_bounds__(512) void fused_all(
    const float* __restrict__ x,
    const float* __restrict__ wq, const float* __restrict__ bq,
    const float* __restrict__ wk, const float* __restrict__ bk,
    const float* __restrict__ wv, const float* __restrict__ bv,
    const float* __restrict__ wo, const float* __restrict__ bo,
    float* __restrict__ out,
    u16* xb, u16* wqb, u16* wkb, u16* wvb, u16* wob,
    u16* qb, u16* kb, u16* vtb, u16* pr, float* rsum)
{
  __shared__ char smem[147456];
  cg::grid_group grid = cg::this_grid();
  const int bid = blockIdx.x;                // 0..255
  const int tid = threadIdx.x;               // 0..511

  // ---------------- phase 0: cast fp32 -> bf16 + zero rowsum ----------------
  {
    if (bid < 8 && tid < 256) {
      float4 z4 = {0.f, 0.f, 0.f, 0.f};
      *(float4*)(rsum + (bid * 256 + tid) * 4) = z4;
    }
    const int g0 = bid * 512 + tid;          // 0..131071
#pragma unroll
    for (int it = 0; it < 12; ++it) {        // 12 x 131072 = 1,572,864 chunks of 8
      const int u = g0 + it * 131072;
      const float* src; u16* dst; int idx8;
      if (u < 1048576) { src = x; dst = xb; idx8 = u; }
      else {
        const int w = (u - 1048576) >> 17;   // 0..3
        idx8 = (u - 1048576) & 131071;
        src = (w == 0) ? wq : (w == 1) ? wk : (w == 2) ? wv : wo;
        dst = (w == 0) ? wqb : (w == 1) ? wkb : (w == 2) ? wvb : wob;
      }
      const int i0 = idx8 * 8;
      float4 f0 = *(const float4*)(src + i0);
      float4 f1 = *(const float4*)(src + i0 + 4);
      short8 o;
      o[0]=(short)f2bf(f0.x); o[1]=(short)f2bf(f0.y); o[2]=(short)f2bf(f0.z); o[3]=(short)f2bf(f0.w);
      o[4]=(short)f2bf(f1.x); o[5]=(short)f2bf(f1.y); o[6]=(short)f2bf(f1.z); o[7]=(short)f2bf(f1.w);
      *(short8*)(dst + i0) = o;
    }
  }
  grid.sync();

  // ---------------- phase 1: proj QKV (z = 0,1,2 per block) ----------------
  {
    const int m0 = ((bid & 7) * 4 + ((bid >> 3) & 3)) * 256;  // XCD owns 4 m-tiles
    const int n0 = (bid >> 5) * 128;
    const int lane = tid & 63, wave = tid >> 6;
    const int quad = lane >> 4, l16 = lane & 15;
    const int wr = (wave >> 1) << 6, wc = (wave & 1) << 6;
#pragma unroll 1
    for (int z = 0; z < 3; ++z) {
      const u16* W = (z == 0) ? wqb : (z == 1) ? wkb : wvb;
      const float* bias = (z == 0) ? bq : (z == 1) ? bk : bv;
      f32x4 acc[4][4]; ACC_ZERO4(acc);
      gemm_256x128(xb, W, m0, n0, 16, smem, acc);
      if (z < 2) {
        store256x128_bf16(acc, bias, n0, (z == 0) ? qb : kb, m0, smem);
      } else {
        u16* t = (u16*)smem;                 // transposed: t[n_local][m_local], 128 x 264
#pragma unroll
        for (int j = 0; j < 4; ++j) {
          const int nn = wc + j * 16 + l16;
          const float bj = bias[n0 + nn];
#pragma unroll
          for (int i = 0; i < 4; ++i) {
            const int mm = wr + i * 16 + quad * 4;
#pragma unroll
            for (int r = 0; r < 4; ++r)
              t[nn * 264 + mm + r] = f2bf(acc[i][j][r] + bj);
          }
        }
        __syncthreads();
        const int b = m0 >> 10, t0 = m0 & 1023;
#pragma unroll
        for (int it = 0; it < 8; ++it) {
          const int L = it * 512 + tid;      // 128 rows x 32 chunks of 8
          const int nn = L >> 5, cc = L & 31;
          *(uint4*)(vtb + ((size_t)b << 20) + (size_t)(n0 + nn) * 1024 + t0 + cc * 8) =
              *(const uint4*)(t + nn * 264 + cc * 8);
        }
      }
      __syncthreads();                       // LDS reads done before next z stages
    }
  }
  grid.sync();

  // ---------------- phase 2: P' = exp(scale*QK^T), causal ----------------
  if (bid < 160) {
    const int b = bid / 20;
    const int t = bid - b * 20;
    const int qi = (t < 2) ? 0 : (t < 6) ? 1 : (t < 12) ? 2 : 3;
    const int pre = (qi == 0) ? 0 : (qi == 1) ? 2 : (qi == 2) ? 6 : 12;
    const int kt = t - pre;
    const int m0 = qi * 256, n0 = kt * 128;
    const u16* A = qb + ((size_t)b << 20);
    const u16* B = kb + ((size_t)b << 20);

    f32x4 acc[4][4]; ACC_ZERO4(acc);
    gemm_256x128(A, B, m0, n0, 16, smem, acc);

    const int lane = tid & 63, wave = tid >> 6;
    const int quad = lane >> 4, l16 = lane & 15;
    const int wr = (wave >> 1) << 6, wc = (wave & 1) << 6;

    float part[4][4];
#pragma unroll
    for (int i = 0; i < 4; ++i)
#pragma unroll
      for (int r = 0; r < 4; ++r) part[i][r] = 0.f;

    u16* tl = (u16*)smem;                    // 256 x 136 u16 repack
#pragma unroll
    for (int j = 0; j < 4; ++j) {
      const int nn = wc + j * 16 + l16;
#pragma unroll
      for (int i = 0; i < 4; ++i) {
        const int mm = wr + i * 16 + quad * 4;
#pragma unroll
        for (int r = 0; r < 4; ++r) {
          float e = __expf(acc[i][j][r] * 0.03125f);
          if ((n0 + nn) > (m0 + mm + r)) e = 0.f;  // causal
          part[i][r] += e;
          tl[(mm + r) * 136 + nn] = f2bf(e);
        }
      }
    }
    float* rs = rsum + b * 1024 + m0;
#pragma unroll
    for (int i = 0; i < 4; ++i)
#pragma unroll
      for (int r = 0; r < 4; ++r) {
        float v = part[i][r];
        v += __shfl_xor(v, 1); v += __shfl_xor(v, 2);
        v += __shfl_xor(v, 4); v += __shfl_xor(v, 8);
        if (l16 == 0) atomicAdd(rs + wr + i * 16 + quad * 4 + r, v);
      }
    __syncthreads();
    u16* C = pr + ((size_t)b << 20);
#pragma unroll
    for (int it = 0; it < 8; ++it) {
      const int L = it * 512 + tid;          // 4096 chunks of 8 u16
      const int mm = L >> 4, cc = L & 15;
      *(uint4*)(C + (size_t)(m0 + mm) * 1024 + n0 + cc * 8) =
          *(const uint4*)(tl + mm * 136 + cc * 8);
    }
  }
  grid.sync();

  // ---------------- phase 3: O = diag(1/l) P' V (O -> xb region) ----------------
  {
    const int b = bid & 7;
    const int u = bid >> 3;                  // 0..31
    const int qi = 3 - (u & 3);
    const int nb = u >> 2;                   // 0..7
    const int m0 = qi * 256, n0 = nb * 128;
    const int nt = (qi + 1) * 4;             // K = (qi+1)*256, BK=64
    const u16* A = pr + ((size_t)b << 20);
    const u16* B = vtb + ((size_t)b << 20);

    f32x4 acc[4][4]; ACC_ZERO4(acc);
    gemm_256x128(A, B, m0, n0, nt, smem, acc);

    const int lane = tid & 63, wave = tid >> 6;
    const int quad = lane >> 4, l16 = lane & 15;
    const int wr = (wave >> 1) << 6, wc = (wave & 1) << 6;
    const float* rs = rsum + b * 1024 + m0;
    u16* tl = (u16*)smem;                    // 256 x 136 u16
#pragma unroll
    for (int i = 0; i < 4; ++i)
#pragma unroll
      for (int r = 0; r < 4; ++r) {
        const int mm = wr + i * 16 + quad * 4 + r;
        const float inv = 1.0f / rs[mm];
#pragma unroll
        for (int j = 0; j < 4; ++j)
          tl[mm * 136 + wc + j * 16 + l16] = f2bf(acc[i][j][r] * inv);
      }
    __syncthreads();
    u16* C = xb + ((size_t)b << 20);         // O reuses x region
#pragma unroll
    for (int it = 0; it < 8; ++it) {
      const int L = it * 512 + tid;
      const int mm = L >> 4, cc = L & 15;
      *(uint4*)(C + (size_t)(m0 + mm) * 1024 + n0 + cc * 8) =
          *(const uint4*)(tl + mm * 136 + cc * 8);
    }
  }
  grid.sync();

  // ---------------- phase 4: out = O Wo^T + bo ----------------
  {
    const int m0 = ((bid & 7) * 4 + ((bid >> 3) & 3)) * 256;
    const int n0 = (bid >> 5) * 128;
    f32x4 acc[4][4]; ACC_ZERO4(acc);
    gemm_256x128(xb, wob, m0, n0, 16, smem, acc);

    const int lane = tid & 63, wave = tid >> 6;
    const int quad = lane >> 4, l16 = lane & 15;
    const int wr = (wave >> 1) << 6, wc = (wave & 1) << 6;
    float* tf = (float*)smem;                // 256 x 132 fp32
#pragma unroll
    for (int j = 0; j < 4; ++j) {
      const int nn = wc + j * 16 + l16;
      const float bj = bo[n0 + nn];
#pragma unroll
      for (int i = 0; i < 4; ++i)
#pragma unroll
        for (int r = 0; r < 4; ++r)
          tf[(wr + i * 16 + quad * 4 + r) * 132 + nn] = acc[i][j][r] + bj;
    }
    __syncthreads();
#pragma unroll
    for (int it = 0; it < 16; ++it) {
      const int L = it * 512 + tid;          // 256 rows x 32 float4
      const int mm = L >> 5, cc = L & 31;
      *(float4*)(out + (size_t)(m0 + mm) * 1024 + n0 + cc * 4) =
          *(const float4*)(tf + mm * 132 + cc * 4);
    }
  }
}

// ---------- launch ----------
extern "C" void kernel_launch(void* const* d_in, const int* in_sizes, int n_in,
                              void* d_out, int out_size, void* d_ws, size_t ws_size,
                              hipStream_t stream) {
  const float* x  = (const float*)d_in[0];
  const float* wq = (const float*)d_in[1];
  const float* bq = (const float*)d_in[2];
  const float* wk = (const float*)d_in[3];
  const float* bk = (const float*)d_in[4];
  const float* wv = (const float*)d_in[5];
  const float* bv = (const float*)d_in[6];
  const float* wo = (const float*)d_in[7];
  const float* bo = (const float*)d_in[8];
  float* out = (float*)d_out;

  char* ws = (char*)d_ws;
  const size_t MB = 1u << 20;
  u16*  xb  = (u16*)(ws);            // 16 MB (x bf16; reused later as O bf16)
  u16*  wqb = (u16*)(ws + 16*MB);
  u16*  wkb = (u16*)(ws + 18*MB);
  u16*  wvb = (u16*)(ws + 20*MB);
  u16*  wob = (u16*)(ws + 22*MB);
  u16*  qb  = (u16*)(ws + 24*MB);
  u16*  kb  = (u16*)(ws + 40*MB);
  u16*  vtb = (u16*)(ws + 56*MB);    // V transposed per batch
  u16*  pr  = (u16*)(ws + 72*MB);    // bf16 unnormalized probs P'
  float* rsum = (float*)(ws + 88*MB);// 32 KB row sums

  void* args[] = {
    (void*)&x, (void*)&wq, (void*)&bq, (void*)&wk, (void*)&bk,
    (void*)&wv, (void*)&bv, (void*)&wo, (void*)&bo, (void*)&out,
    (void*)&xb, (void*)&wqb, (void*)&wkb, (void*)&wvb, (void*)&wob,
    (void*)&qb, (void*)&kb, (void*)&vtb, (void*)&pr, (void*)&rsum
  };
  hipLaunchCooperativeKernel((const void*)fused_all, dim3(256), dim3(512),
                             args, 0, stream);
}

// Round 9
// 221.760 us; speedup vs baseline: 1.7668x; 1.7668x over previous
//
#include <hip/hip_runtime.h>

typedef unsigned short u16;
typedef __attribute__((ext_vector_type(8))) short short8;
typedef __attribute__((ext_vector_type(4))) float f32x4;

// ---------- helpers ----------

__device__ __forceinline__ u16 f2bf(float f) {
  unsigned u = __builtin_bit_cast(unsigned, f);
  u += 0x7fffu + ((u >> 16) & 1u);   // RNE
  return (u16)(u >> 16);
}

__device__ __forceinline__ void gload16(const void* g, void* l) {
  __builtin_amdgcn_global_load_lds(
      (const __attribute__((address_space(1))) unsigned*)g,
      (__attribute__((address_space(3))) unsigned*)l, 16, 0, 0);
}

#define MFMA16(a, b, c) __builtin_amdgcn_mfma_f32_16x16x32_bf16(a, b, c, 0, 0, 0)

// ================================================================
// Round-3 proven 256x128 GEMM core: BK=64, 3 LDS buffers, dist-2
// prefetch, counted vmcnt(6), ONE barrier per K-tile.
// ================================================================

#define PTILE(RB_C, RB_N, DOSTAGE, VM, LAST)                                  \
  {                                                                           \
    char* cA = sA0 + cur * 49152;                                             \
    /* ---- phase 0 ---- */                                                   \
    if (DOSTAGE) {                                                            \
      const int ns = (cur + 2 >= 3) ? cur - 1 : cur + 2;                      \
      char* dA = sA0 + ns * 49152;                                            \
      _Pragma("unroll") for (int j = 0; j < 3; ++j) {                         \
        gload16(ga[j], dA + la[j]); ga[j] += 64; }                            \
    }                                                                         \
    _Pragma("unroll") for (int kk = 0; kk < 2; ++kk)                          \
      _Pragma("unroll") for (int i = 0; i < 2; ++i) {                         \
        const int rm = wr + 32 + i * 16 + l16;                                \
        a1f[kk][i] = *(const short8*)(cA + rm * 128 +                         \
            (((kk << 2) + quad) ^ (rm & 7)) * 16);                            \
      }                                                                       \
    asm volatile("s_waitcnt lgkmcnt(4)" ::: "memory");                        \
    __builtin_amdgcn_sched_barrier(0);                                        \
    __builtin_amdgcn_s_setprio(1);                                            \
    _Pragma("unroll") for (int kk = 0; kk < 2; ++kk)                          \
      _Pragma("unroll") for (int i = 0; i < 2; ++i)                           \
        _Pragma("unroll") for (int j = 0; j < 4; ++j)                         \
          acc[i][j] = MFMA16(a0f[kk][i], RB_C[kk][j], acc[i][j]);             \
    __builtin_amdgcn_s_setprio(0);                                            \
    /* ---- phase 1 ---- */                                                   \
    if (DOSTAGE) {                                                            \
      const int ns = (cur + 2 >= 3) ? cur - 1 : cur + 2;                      \
      char* dA = sA0 + ns * 49152; char* dB = dA + 32768;                     \
      gload16(ga[3], dA + la[3]); ga[3] += 64;                                \
      _Pragma("unroll") for (int j = 0; j < 2; ++j) {                         \
        gload16(gb[j], dB + lb[j]); gb[j] += 64; }                            \
    }                                                                         \
    if (!(LAST)) {                                                            \
      asm volatile("s_waitcnt vmcnt(" #VM ") lgkmcnt(0)" ::: "memory");       \
      __builtin_amdgcn_s_barrier();                                           \
      asm volatile("" ::: "memory");                                          \
      const int nc = (cur + 1 >= 3) ? 0 : cur + 1;                            \
      char* nA = sA0 + nc * 49152; char* nB = nA + 32768;                     \
      _Pragma("unroll") for (int kk = 0; kk < 2; ++kk)                        \
        _Pragma("unroll") for (int j = 0; j < 4; ++j) {                       \
          const int rn = wc + j * 16 + l16;                                   \
          RB_N[kk][j] = *(const short8*)(nB + rn * 128 +                      \
              (((kk << 2) + quad) ^ (rn & 7)) * 16);                          \
        }                                                                     \
      _Pragma("unroll") for (int kk = 0; kk < 2; ++kk)                        \
        _Pragma("unroll") for (int i = 0; i < 2; ++i) {                       \
          const int rm = wr + i * 16 + l16;                                   \
          a0f[kk][i] = *(const short8*)(nA + rm * 128 +                       \
              (((kk << 2) + quad) ^ (rm & 7)) * 16);                          \
        }                                                                     \
    } else {                                                                  \
      asm volatile("s_waitcnt lgkmcnt(0)" ::: "memory");                      \
    }                                                                         \
    __builtin_amdgcn_sched_barrier(0);                                        \
    __builtin_amdgcn_s_setprio(1);                                            \
    _Pragma("unroll") for (int kk = 0; kk < 2; ++kk)                          \
      _Pragma("unroll") for (int i = 0; i < 2; ++i)                           \
        _Pragma("unroll") for (int j = 0; j < 4; ++j)                         \
          acc[2 + i][j] = MFMA16(a1f[kk][i], RB_C[kk][j], acc[2 + i][j]);     \
    __builtin_amdgcn_s_setprio(0);                                            \
    cur = (cur + 1 >= 3) ? 0 : cur + 1;                                       \
  }

__device__ __forceinline__ void gemm_256x128(
    const u16* __restrict__ A, const u16* __restrict__ B,
    int m0, int n0, int ntiles, char* smem, f32x4 acc[4][4])
{
  const int tid  = threadIdx.x;          // 0..511
  const int lane = tid & 63;
  const int quad = lane >> 4;
  const int l16  = lane & 15;
  const int wave = tid >> 6;             // 0..7
  const int wr   = (wave >> 1) << 6;     // 0,64,128,192
  const int wc   = (wave & 1) << 6;      // 0,64

  const u16* ga[4]; int la[4];
  const u16* gb[2]; int lb[2];
#pragma unroll
  for (int j = 0; j < 4; ++j) {
    const int L = j * 512 + tid;         // 2048 chunks: 256 rows x 8
    const int r = L >> 3;
    const int c = (L & 7) ^ (r & 7);
    la[j] = L * 16;
    ga[j] = A + (size_t)(m0 + r) * 1024 + c * 8;
  }
#pragma unroll
  for (int j = 0; j < 2; ++j) {
    const int L = j * 512 + tid;         // 1024 chunks: 128 rows x 8
    const int r = L >> 3;
    const int c = (L & 7) ^ (r & 7);
    lb[j] = L * 16;
    gb[j] = B + (size_t)(n0 + r) * 1024 + c * 8;
  }
  char* const sA0 = smem;                // buf b: A at b*49152, B at +32768

  short8 bfr0[2][4], bfr1[2][4];         // B frags, double-buffered
  short8 a0f[2][2], a1f[2][2];           // A frags rows 0..31 / 32..63

  // prologue: stage tiles 0 and 1 (6 gloads each)
  {
    char* dA = sA0; char* dB = sA0 + 32768;
#pragma unroll
    for (int j = 0; j < 4; ++j) { gload16(ga[j], dA + la[j]); ga[j] += 64; }
#pragma unroll
    for (int j = 0; j < 2; ++j) { gload16(gb[j], dB + lb[j]); gb[j] += 64; }
    dA = sA0 + 49152; dB = dA + 32768;
#pragma unroll
    for (int j = 0; j < 4; ++j) { gload16(ga[j], dA + la[j]); ga[j] += 64; }
#pragma unroll
    for (int j = 0; j < 2; ++j) { gload16(gb[j], dB + lb[j]); gb[j] += 64; }
  }
  asm volatile("s_waitcnt vmcnt(6)" ::: "memory");   // tile0 done, tile1 in flight
  __builtin_amdgcn_s_barrier();
  asm volatile("" ::: "memory");
  {
    char* nA = sA0; char* nB = sA0 + 32768;
#pragma unroll
    for (int kk = 0; kk < 2; ++kk)
#pragma unroll
      for (int j = 0; j < 4; ++j) {
        const int rn = wc + j * 16 + l16;
        bfr0[kk][j] = *(const short8*)(nB + rn * 128 + (((kk << 2) + quad) ^ (rn & 7)) * 16);
      }
#pragma unroll
    for (int kk = 0; kk < 2; ++kk)
#pragma unroll
      for (int i = 0; i < 2; ++i) {
        const int rm = wr + i * 16 + l16;
        a0f[kk][i] = *(const short8*)(nA + rm * 128 + (((kk << 2) + quad) ^ (rm & 7)) * 16);
      }
  }

  int cur = 0;
  const int npair = (ntiles >> 1) - 1;
#pragma unroll 1
  for (int it = 0; it < npair; ++it) {
    PTILE(bfr0, bfr1, true, 6, false);
    PTILE(bfr1, bfr0, true, 6, false);
  }
  PTILE(bfr0, bfr1, false, 0, false);
  PTILE(bfr1, bfr0, false, 0, true);
  __syncthreads();                       // epilogue may rewrite LDS
}

#define ACC_ZERO4(acc) { _Pragma("unroll") for (int i=0;i<4;++i) \
  _Pragma("unroll") for (int j=0;j<4;++j) \
  _Pragma("unroll") for (int r=0;r<4;++r) acc[i][j][r]=0.f; }

// ---------- epilogue: 256x128 acc(+bias) -> bf16 C via LDS repack ----------
__device__ __forceinline__ void store256x128_bf16(
    f32x4 acc[4][4], const float* bias, int n0,
    u16* C, int m0, char* smem)
{
  const int tid = threadIdx.x, lane = tid & 63, wave = tid >> 6;
  const int quad = lane >> 4, l16 = lane & 15;
  const int wr = (wave >> 1) << 6, wc = (wave & 1) << 6;
  u16* t = (u16*)smem;                       // 256 x 136 u16
#pragma unroll
  for (int j = 0; j < 4; ++j) {
    const int nn = wc + j * 16 + l16;
    const float bj = bias[n0 + nn];
#pragma unroll
    for (int i = 0; i < 4; ++i) {
      const int mm = wr + i * 16 + quad * 4;
#pragma unroll
      for (int r = 0; r < 4; ++r)
        t[(mm + r) * 136 + nn] = f2bf(acc[i][j][r] + bj);
    }
  }
  __syncthreads();
#pragma unroll
  for (int it = 0; it < 8; ++it) {
    const int L = it * 512 + tid;              // 4096 chunks of 8 u16
    const int mm = L >> 4, cc = L & 15;
    *(uint4*)(C + (size_t)(m0 + mm) * 1024 + n0 + cc * 8) =
        *(const uint4*)(t + mm * 136 + cc * 8);
  }
}

// ---------- kernel 1: cast fp32 -> bf16 (x + 4 weights) + zero rowsum ----------
__global__ __launch_bounds__(256) void cast_inputs(
    const float* __restrict__ x,  const float* __restrict__ wq,
    const float* __restrict__ wk, const float* __restrict__ wv,
    const float* __restrict__ wo,
    u16* xb, u16* wqb, u16* wkb, u16* wvb, u16* wob, float* rsum)
{
  int b = blockIdx.x;
  if (b < 8) {                               // fold rowsum zeroing (8192 floats)
    float4 z = {0.f, 0.f, 0.f, 0.f};
    *(float4*)(rsum + (b * 256 + threadIdx.x) * 4) = z;
  }
  const float* src; u16* dst; int base;
  if (b < 4096) { src = x; dst = xb; base = b * 2048; }
  else {
    int r = (b - 4096) >> 9, bb = (b - 4096) & 511;
    base = bb * 2048;
    src = (r == 0) ? wq : (r == 1) ? wk : (r == 2) ? wv : wo;
    dst = (r == 0) ? wqb : (r == 1) ? wkb : (r == 2) ? wvb : wob;
  }
  int i0 = base + threadIdx.x * 8;
  float4 f0 = *(const float4*)(src + i0);
  float4 f1 = *(const float4*)(src + i0 + 4);
  short8 o;
  o[0]=(short)f2bf(f0.x); o[1]=(short)f2bf(f0.y); o[2]=(short)f2bf(f0.z); o[3]=(short)f2bf(f0.w);
  o[4]=(short)f2bf(f1.x); o[5]=(short)f2bf(f1.y); o[6]=(short)f2bf(f1.z); o[7]=(short)f2bf(f1.w);
  *(short8*)(dst + i0) = o;
}

// ---------- kernel 2: Q,K projections only (V moved to the mix kernel) ----------
// grid (256, 2): x = XCD-chunked tile id, y = which weight (q/k). 2 clean rounds.
__global__ __launch_bounds__(512, 2) void proj_qk(
    const u16* __restrict__ xb,
    const u16* __restrict__ wqb, const u16* __restrict__ wkb,
    const float* __restrict__ bq, const float* __restrict__ bk,
    u16* q, u16* k)
{
  __shared__ char smem[147456];
  const int z = blockIdx.y;
  const u16* W = (z == 0) ? wqb : wkb;
  const float* bias = (z == 0) ? bq : bk;
  const int id = blockIdx.x;                 // 0..255
  const int m0 = ((id & 7) * 4 + ((id >> 3) & 3)) * 256;   // XCD owns 4 m-tiles
  const int n0 = (id >> 5) * 128;

  f32x4 acc[4][4]; ACC_ZERO4(acc);
  gemm_256x128(xb, W, m0, n0, 16, smem, acc);
  store256x128_bf16(acc, bias, n0, (z == 0) ? q : k, m0, smem);
}

// ---------- kernel 3 (packed): qk_exp (blocks 0..159) + proj_V (blocks 160..415) ----------
// Independent outputs: qk writes pr/rsum (reads qb,kb); proj_V writes vtb (reads xb,wvb).
__global__ __launch_bounds__(512, 2) void mix_qk_projv(
    const u16* __restrict__ qb, const u16* __restrict__ kb,
    u16* __restrict__ pr, float* __restrict__ rsum,
    const u16* __restrict__ xb, const u16* __restrict__ wvb,
    const float* __restrict__ bv, u16* __restrict__ vt)
{
  __shared__ char smem[147456];
  const int bid = blockIdx.x;                // 0..415
  const int tid = threadIdx.x;
  const int lane = tid & 63, wave = tid >> 6;
  const int quad = lane >> 4, l16 = lane & 15;
  const int wr = (wave >> 1) << 6, wc = (wave & 1) << 6;

  if (bid < 160) {
    // ---- P' = exp(scale*QK^T), causal; 256x128 tiles ----
    const int b = bid / 20;
    const int t = bid - b * 20;
    const int qi = (t < 2) ? 0 : (t < 6) ? 1 : (t < 12) ? 2 : 3;
    const int pre = (qi == 0) ? 0 : (qi == 1) ? 2 : (qi == 2) ? 6 : 12;
    const int kt = t - pre;
    const int m0 = qi * 256, n0 = kt * 128;
    const u16* A = qb + ((size_t)b << 20);
    const u16* B = kb + ((size_t)b << 20);

    f32x4 acc[4][4]; ACC_ZERO4(acc);
    gemm_256x128(A, B, m0, n0, 16, smem, acc);

    float part[4][4];
#pragma unroll
    for (int i = 0; i < 4; ++i)
#pragma unroll
      for (int r = 0; r < 4; ++r) part[i][r] = 0.f;

    u16* tl = (u16*)smem;                    // 256 x 136 u16 repack
#pragma unroll
    for (int j = 0; j < 4; ++j) {
      const int nn = wc + j * 16 + l16;
#pragma unroll
      for (int i = 0; i < 4; ++i) {
        const int mm = wr + i * 16 + quad * 4;
#pragma unroll
        for (int r = 0; r < 4; ++r) {
          float e = __expf(acc[i][j][r] * 0.03125f);
          if ((n0 + nn) > (m0 + mm + r)) e = 0.f;  // causal
          part[i][r] += e;
          tl[(mm + r) * 136 + nn] = f2bf(e);
        }
      }
    }
    float* rs = rsum + b * 1024 + m0;
#pragma unroll
    for (int i = 0; i < 4; ++i)
#pragma unroll
      for (int r = 0; r < 4; ++r) {
        float v = part[i][r];
        v += __shfl_xor(v, 1); v += __shfl_xor(v, 2);
        v += __shfl_xor(v, 4); v += __shfl_xor(v, 8);
        if (l16 == 0) atomicAdd(rs + wr + i * 16 + quad * 4 + r, v);
      }
    __syncthreads();
    u16* C = pr + ((size_t)b << 20);
#pragma unroll
    for (int it = 0; it < 8; ++it) {
      const int L = it * 512 + tid;          // 4096 chunks of 8 u16
      const int mm = L >> 4, cc = L & 15;
      *(uint4*)(C + (size_t)(m0 + mm) * 1024 + n0 + cc * 8) =
          *(const uint4*)(tl + mm * 136 + cc * 8);
    }
  } else {
    // ---- V projection, stored transposed per batch ----
    const int id = bid - 160;                // 0..255 (160%8==0: XCD mapping kept)
    const int m0 = ((id & 7) * 4 + ((id >> 3) & 3)) * 256;
    const int n0 = (id >> 5) * 128;

    f32x4 acc[4][4]; ACC_ZERO4(acc);
    gemm_256x128(xb, wvb, m0, n0, 16, smem, acc);

    u16* t = (u16*)smem;                     // transposed: t[n_local][m_local], 128 x 264
#pragma unroll
    for (int j = 0; j < 4; ++j) {
      const int nn = wc + j * 16 + l16;
      const float bj = bv[n0 + nn];
#pragma unroll
      for (int i = 0; i < 4; ++i) {
        const int mm = wr + i * 16 + quad * 4;
#pragma unroll
        for (int r = 0; r < 4; ++r)
          t[nn * 264 + mm + r] = f2bf(acc[i][j][r] + bj);
      }
    }
    __syncthreads();
    const int b = m0 >> 10, t0 = m0 & 1023;
#pragma unroll
    for (int it = 0; it < 8; ++it) {
      const int L = it * 512 + tid;          // 128 rows x 32 chunks of 8
      const int nn = L >> 5, cc = L & 31;
      *(uint4*)(vt + ((size_t)b << 20) + (size_t)(n0 + nn) * 1024 + t0 + cc * 8) =
          *(const uint4*)(t + nn * 264 + cc * 8);
    }
  }
}

// ---------- kernel 4: O = diag(1/l) P' V; 256x128 tiles, variable K ----------
// grid = 256 blocks exactly: 8 batches x 4 q-tiles x 8 n-tiles
__global__ __launch_bounds__(512, 2) void pv256(
    const u16* __restrict__ probs, const u16* __restrict__ vt,
    const float* __restrict__ rowsum, u16* __restrict__ o)
{
  __shared__ char smem[147456];
  const int id = blockIdx.x;                 // 0..255
  const int b = id & 7;
  const int u = id >> 3;                     // 0..31
  const int qi = 3 - (u & 3);                // big-K blocks first
  const int nb = u >> 2;                     // 0..7
  const int m0 = qi * 256, n0 = nb * 128;
  const int nt = (qi + 1) * 4;               // K = (qi+1)*256, BK=64
  const u16* A = probs + ((size_t)b << 20);
  const u16* B = vt + ((size_t)b << 20);

  f32x4 acc[4][4]; ACC_ZERO4(acc);
  gemm_256x128(A, B, m0, n0, nt, smem, acc);

  const int tid = threadIdx.x, lane = tid & 63, wave = tid >> 6;
  const int quad = lane >> 4, l16 = lane & 15;
  const int wr = (wave >> 1) << 6, wc = (wave & 1) << 6;
  const float* rs = rowsum + b * 1024 + m0;
  u16* tl = (u16*)smem;                      // 256 x 136 u16
#pragma unroll
  for (int i = 0; i < 4; ++i)
#pragma unroll
    for (int r = 0; r < 4; ++r) {
      const int mm = wr + i * 16 + quad * 4 + r;
      const float inv = 1.0f / rs[mm];
#pragma unroll
      for (int j = 0; j < 4; ++j)
        tl[mm * 136 + wc + j * 16 + l16] = f2bf(acc[i][j][r] * inv);
    }
  __syncthreads();
  u16* C = o + ((size_t)b << 20);
#pragma unroll
  for (int it = 0; it < 8; ++it) {
    const int L = it * 512 + tid;
    const int mm = L >> 4, cc = L & 15;
    *(uint4*)(C + (size_t)(m0 + mm) * 1024 + n0 + cc * 8) =
        *(const uint4*)(tl + mm * 136 + cc * 8);
  }
}

// ---------- kernel 5: out = O Wo^T + bo; fp32 epilogue ----------
__global__ __launch_bounds__(512, 2) void proj_o(
    const u16* __restrict__ ob, const u16* __restrict__ wob,
    const float* __restrict__ bo, float* __restrict__ out)
{
  __shared__ char smem[147456];
  const int id = blockIdx.x;                 // 0..255
  const int m0 = ((id & 7) * 4 + ((id >> 3) & 3)) * 256;
  const int n0 = (id >> 5) * 128;
  f32x4 acc[4][4]; ACC_ZERO4(acc);
  gemm_256x128(ob, wob, m0, n0, 16, smem, acc);

  const int tid = threadIdx.x, lane = tid & 63, wave = tid >> 6;
  const int quad = lane >> 4, l16 = lane & 15;
  const int wr = (wave >> 1) << 6, wc = (wave & 1) << 6;
  float* tf = (float*)smem;                  // 256 x 132 fp32
#pragma unroll
  for (int j = 0; j < 4; ++j) {
    const int nn = wc + j * 16 + l16;
    const float bj = bo[n0 + nn];
#pragma unroll
    for (int i = 0; i < 4; ++i)
#pragma unroll
      for (int r = 0; r < 4; ++r)
        tf[(wr + i * 16 + quad * 4 + r) * 132 + nn] = acc[i][j][r] + bj;
  }
  __syncthreads();
#pragma unroll
  for (int it = 0; it < 16; ++it) {
    const int L = it * 512 + tid;            // 256 rows x 32 float4
    const int mm = L >> 5, cc = L & 31;
    *(float4*)(out + (size_t)(m0 + mm) * 1024 + n0 + cc * 4) =
        *(const float4*)(tf + mm * 132 + cc * 4);
  }
}

// ---------- launch ----------
extern "C" void kernel_launch(void* const* d_in, const int* in_sizes, int n_in,
                              void* d_out, int out_size, void* d_ws, size_t ws_size,
                              hipStream_t stream) {
  const float* x  = (const float*)d_in[0];
  const float* wq = (const float*)d_in[1];
  const float* bq = (const float*)d_in[2];
  const float* wk = (const float*)d_in[3];
  const float* bk = (const float*)d_in[4];
  const float* wv = (const float*)d_in[5];
  const float* bv = (const float*)d_in[6];
  const float* wo = (const float*)d_in[7];
  const float* bo = (const float*)d_in[8];
  float* out = (float*)d_out;

  char* ws = (char*)d_ws;
  const size_t MB = 1u << 20;
  u16*  xb  = (u16*)(ws);            // 16 MB (x bf16; reused later as O bf16)
  u16*  wqb = (u16*)(ws + 16*MB);
  u16*  wkb = (u16*)(ws + 18*MB);
  u16*  wvb = (u16*)(ws + 20*MB);
  u16*  wob = (u16*)(ws + 22*MB);
  u16*  qb  = (u16*)(ws + 24*MB);
  u16*  kb  = (u16*)(ws + 40*MB);
  u16*  vtb = (u16*)(ws + 56*MB);    // V transposed per batch
  u16*  pr  = (u16*)(ws + 72*MB);    // bf16 unnormalized probs P'
  float* rsum = (float*)(ws + 88*MB);// 32 KB row sums

  cast_inputs<<<6144, 256, 0, stream>>>(x, wq, wk, wv, wo, xb, wqb, wkb, wvb, wob, rsum);
  proj_qk<<<dim3(256, 2), 512, 0, stream>>>(xb, wqb, wkb, bq, bk, qb, kb);
  mix_qk_projv<<<416, 512, 0, stream>>>(qb, kb, pr, rsum, xb, wvb, bv, vtb);
  pv256<<<256, 512, 0, stream>>>(pr, vtb, rsum, xb /* O reuses x region */);
  proj_o<<<256, 512, 0, stream>>>(xb, wob, bo, out);
}

// Round 10
// 217.415 us; speedup vs baseline: 1.8021x; 1.0200x over previous
//
#include <hip/hip_runtime.h>

typedef unsigned short u16;
typedef __attribute__((ext_vector_type(8))) short short8;
typedef __attribute__((ext_vector_type(4))) float f32x4;

// ---------- helpers ----------

__device__ __forceinline__ u16 f2bf(float f) {
  unsigned u = __builtin_bit_cast(unsigned, f);
  u += 0x7fffu + ((u >> 16) & 1u);   // RNE
  return (u16)(u >> 16);
}

__device__ __forceinline__ void gload16(const void* g, void* l) {
  __builtin_amdgcn_global_load_lds(
      (const __attribute__((address_space(1))) unsigned*)g,
      (__attribute__((address_space(3))) unsigned*)l, 16, 0, 0);
}

#define MFMA16(a, b, c) __builtin_amdgcn_mfma_f32_16x16x32_bf16(a, b, c, 0, 0, 0)

// ================================================================
// Round-3 proven 256x128 GEMM core: BK=64, 3 LDS buffers, dist-2
// prefetch, counted vmcnt(6), ONE barrier per K-tile.
// ================================================================

#define PTILE(RB_C, RB_N, DOSTAGE, VM, LAST)                                  \
  {                                                                           \
    char* cA = sA0 + cur * 49152;                                             \
    /* ---- phase 0 ---- */                                                   \
    if (DOSTAGE) {                                                            \
      const int ns = (cur + 2 >= 3) ? cur - 1 : cur + 2;                      \
      char* dA = sA0 + ns * 49152;                                            \
      _Pragma("unroll") for (int j = 0; j < 3; ++j) {                         \
        gload16(ga[j], dA + la[j]); ga[j] += 64; }                            \
    }                                                                         \
    _Pragma("unroll") for (int kk = 0; kk < 2; ++kk)                          \
      _Pragma("unroll") for (int i = 0; i < 2; ++i) {                         \
        const int rm = wr + 32 + i * 16 + l16;                                \
        a1f[kk][i] = *(const short8*)(cA + rm * 128 +                         \
            (((kk << 2) + quad) ^ (rm & 7)) * 16);                            \
      }                                                                       \
    asm volatile("s_waitcnt lgkmcnt(4)" ::: "memory");                        \
    __builtin_amdgcn_sched_barrier(0);                                        \
    __builtin_amdgcn_s_setprio(1);                                            \
    _Pragma("unroll") for (int kk = 0; kk < 2; ++kk)                          \
      _Pragma("unroll") for (int i = 0; i < 2; ++i)                           \
        _Pragma("unroll") for (int j = 0; j < 4; ++j)                         \
          acc[i][j] = MFMA16(a0f[kk][i], RB_C[kk][j], acc[i][j]);             \
    __builtin_amdgcn_s_setprio(0);                                            \
    /* ---- phase 1 ---- */                                                   \
    if (DOSTAGE) {                                                            \
      const int ns = (cur + 2 >= 3) ? cur - 1 : cur + 2;                      \
      char* dA = sA0 + ns * 49152; char* dB = dA + 32768;                     \
      gload16(ga[3], dA + la[3]); ga[3] += 64;                                \
      _Pragma("unroll") for (int j = 0; j < 2; ++j) {                         \
        gload16(gb[j], dB + lb[j]); gb[j] += 64; }                            \
    }                                                                         \
    if (!(LAST)) {                                                            \
      asm volatile("s_waitcnt vmcnt(" #VM ") lgkmcnt(0)" ::: "memory");       \
      __builtin_amdgcn_s_barrier();                                           \
      asm volatile("" ::: "memory");                                          \
      const int nc = (cur + 1 >= 3) ? 0 : cur + 1;                            \
      char* nA = sA0 + nc * 49152; char* nB = nA + 32768;                     \
      _Pragma("unroll") for (int kk = 0; kk < 2; ++kk)                        \
        _Pragma("unroll") for (int j = 0; j < 4; ++j) {                       \
          const int rn = wc + j * 16 + l16;                                   \
          RB_N[kk][j] = *(const short8*)(nB + rn * 128 +                      \
              (((kk << 2) + quad) ^ (rn & 7)) * 16);                          \
        }                                                                     \
      _Pragma("unroll") for (int kk = 0; kk < 2; ++kk)                        \
        _Pragma("unroll") for (int i = 0; i < 2; ++i) {                       \
          const int rm = wr + i * 16 + l16;                                   \
          a0f[kk][i] = *(const short8*)(nA + rm * 128 +                       \
              (((kk << 2) + quad) ^ (rm & 7)) * 16);                          \
        }                                                                     \
    } else {                                                                  \
      asm volatile("s_waitcnt lgkmcnt(0)" ::: "memory");                      \
    }                                                                         \
    __builtin_amdgcn_sched_barrier(0);                                        \
    __builtin_amdgcn_s_setprio(1);                                            \
    _Pragma("unroll") for (int kk = 0; kk < 2; ++kk)                          \
      _Pragma("unroll") for (int i = 0; i < 2; ++i)                           \
        _Pragma("unroll") for (int j = 0; j < 4; ++j)                         \
          acc[2 + i][j] = MFMA16(a1f[kk][i], RB_C[kk][j], acc[2 + i][j]);     \
    __builtin_amdgcn_s_setprio(0);                                            \
    cur = (cur + 1 >= 3) ? 0 : cur + 1;                                       \
  }

__device__ __forceinline__ void gemm_256x128(
    const u16* __restrict__ A, const u16* __restrict__ B,
    int m0, int n0, int ntiles, char* smem, f32x4 acc[4][4])
{
  const int tid  = threadIdx.x;          // 0..511
  const int lane = tid & 63;
  const int quad = lane >> 4;
  const int l16  = lane & 15;
  const int wave = tid >> 6;             // 0..7
  const int wr   = (wave >> 1) << 6;     // 0,64,128,192
  const int wc   = (wave & 1) << 6;      // 0,64

  const u16* ga[4]; int la[4];
  const u16* gb[2]; int lb[2];
#pragma unroll
  for (int j = 0; j < 4; ++j) {
    const int L = j * 512 + tid;         // 2048 chunks: 256 rows x 8
    const int r = L >> 3;
    const int c = (L & 7) ^ (r & 7);
    la[j] = L * 16;
    ga[j] = A + (size_t)(m0 + r) * 1024 + c * 8;
  }
#pragma unroll
  for (int j = 0; j < 2; ++j) {
    const int L = j * 512 + tid;         // 1024 chunks: 128 rows x 8
    const int r = L >> 3;
    const int c = (L & 7) ^ (r & 7);
    lb[j] = L * 16;
    gb[j] = B + (size_t)(n0 + r) * 1024 + c * 8;
  }
  char* const sA0 = smem;                // buf b: A at b*49152, B at +32768

  short8 bfr0[2][4], bfr1[2][4];         // B frags, double-buffered
  short8 a0f[2][2], a1f[2][2];           // A frags rows 0..31 / 32..63

  // prologue: stage tiles 0 and 1 (6 gloads each)
  {
    char* dA = sA0; char* dB = sA0 + 32768;
#pragma unroll
    for (int j = 0; j < 4; ++j) { gload16(ga[j], dA + la[j]); ga[j] += 64; }
#pragma unroll
    for (int j = 0; j < 2; ++j) { gload16(gb[j], dB + lb[j]); gb[j] += 64; }
    dA = sA0 + 49152; dB = dA + 32768;
#pragma unroll
    for (int j = 0; j < 4; ++j) { gload16(ga[j], dA + la[j]); ga[j] += 64; }
#pragma unroll
    for (int j = 0; j < 2; ++j) { gload16(gb[j], dB + lb[j]); gb[j] += 64; }
  }
  asm volatile("s_waitcnt vmcnt(6)" ::: "memory");   // tile0 done, tile1 in flight
  __builtin_amdgcn_s_barrier();
  asm volatile("" ::: "memory");
  {
    char* nA = sA0; char* nB = sA0 + 32768;
#pragma unroll
    for (int kk = 0; kk < 2; ++kk)
#pragma unroll
      for (int j = 0; j < 4; ++j) {
        const int rn = wc + j * 16 + l16;
        bfr0[kk][j] = *(const short8*)(nB + rn * 128 + (((kk << 2) + quad) ^ (rn & 7)) * 16);
      }
#pragma unroll
    for (int kk = 0; kk < 2; ++kk)
#pragma unroll
      for (int i = 0; i < 2; ++i) {
        const int rm = wr + i * 16 + l16;
        a0f[kk][i] = *(const short8*)(nA + rm * 128 + (((kk << 2) + quad) ^ (rm & 7)) * 16);
      }
  }

  int cur = 0;
  const int npair = (ntiles >> 1) - 1;
#pragma unroll 1
  for (int it = 0; it < npair; ++it) {
    PTILE(bfr0, bfr1, true, 6, false);
    PTILE(bfr1, bfr0, true, 6, false);
  }
  PTILE(bfr0, bfr1, false, 0, false);
  PTILE(bfr1, bfr0, false, 0, true);
  __syncthreads();                       // epilogue may rewrite LDS
}

#define ACC_ZERO4(acc) { _Pragma("unroll") for (int i=0;i<4;++i) \
  _Pragma("unroll") for (int j=0;j<4;++j) \
  _Pragma("unroll") for (int r=0;r<4;++r) acc[i][j][r]=0.f; }

// ---------- epilogue: 256x128 acc(+bias) -> bf16 C via LDS repack ----------
__device__ __forceinline__ void store256x128_bf16(
    f32x4 acc[4][4], const float* bias, int n0,
    u16* C, int m0, char* smem)
{
  const int tid = threadIdx.x, lane = tid & 63, wave = tid >> 6;
  const int quad = lane >> 4, l16 = lane & 15;
  const int wr = (wave >> 1) << 6, wc = (wave & 1) << 6;
  u16* t = (u16*)smem;                       // 256 x 136 u16
#pragma unroll
  for (int j = 0; j < 4; ++j) {
    const int nn = wc + j * 16 + l16;
    const float bj = bias[n0 + nn];
#pragma unroll
    for (int i = 0; i < 4; ++i) {
      const int mm = wr + i * 16 + quad * 4;
#pragma unroll
      for (int r = 0; r < 4; ++r)
        t[(mm + r) * 136 + nn] = f2bf(acc[i][j][r] + bj);
    }
  }
  __syncthreads();
#pragma unroll
  for (int it = 0; it < 8; ++it) {
    const int L = it * 512 + tid;              // 4096 chunks of 8 u16
    const int mm = L >> 4, cc = L & 15;
    *(uint4*)(C + (size_t)(m0 + mm) * 1024 + n0 + cc * 8) =
        *(const uint4*)(t + mm * 136 + cc * 8);
  }
}

// ---------- kernel 1: cast fp32 -> bf16 (x + 4 weights) + zero rowsum ----------
__global__ __launch_bounds__(256) void cast_inputs(
    const float* __restrict__ x,  const float* __restrict__ wq,
    const float* __restrict__ wk, const float* __restrict__ wv,
    const float* __restrict__ wo,
    u16* xb, u16* wqb, u16* wkb, u16* wvb, u16* wob, float* rsum)
{
  int b = blockIdx.x;
  if (b < 8) {                               // fold rowsum zeroing (8192 floats)
    float4 z = {0.f, 0.f, 0.f, 0.f};
    *(float4*)(rsum + (b * 256 + threadIdx.x) * 4) = z;
  }
  const float* src; u16* dst; int base;
  if (b < 4096) { src = x; dst = xb; base = b * 2048; }
  else {
    int r = (b - 4096) >> 9, bb = (b - 4096) & 511;
    base = bb * 2048;
    src = (r == 0) ? wq : (r == 1) ? wk : (r == 2) ? wv : wo;
    dst = (r == 0) ? wqb : (r == 1) ? wkb : (r == 2) ? wvb : wob;
  }
  int i0 = base + threadIdx.x * 8;
  float4 f0 = *(const float4*)(src + i0);
  float4 f1 = *(const float4*)(src + i0 + 4);
  short8 o;
  o[0]=(short)f2bf(f0.x); o[1]=(short)f2bf(f0.y); o[2]=(short)f2bf(f0.z); o[3]=(short)f2bf(f0.w);
  o[4]=(short)f2bf(f1.x); o[5]=(short)f2bf(f1.y); o[6]=(short)f2bf(f1.z); o[7]=(short)f2bf(f1.w);
  *(short8*)(dst + i0) = o;
}

// ---------- kernel 2: fused QKV projection (round-3 proven) ----------
// grid (256, 3): x = XCD-chunked tile id, y = which weight (q/k/v).
__global__ __launch_bounds__(512, 2) void proj_qkv(
    const u16* __restrict__ xb,
    const u16* __restrict__ wqb, const u16* __restrict__ wkb, const u16* __restrict__ wvb,
    const float* __restrict__ bq, const float* __restrict__ bk, const float* __restrict__ bv,
    u16* q, u16* k, u16* vt)
{
  __shared__ char smem[147456];
  const int z = blockIdx.y;
  const u16* W = (z == 0) ? wqb : (z == 1) ? wkb : wvb;
  const float* bias = (z == 0) ? bq : (z == 1) ? bk : bv;
  const int id = blockIdx.x;                 // 0..255
  const int m0 = ((id & 7) * 4 + ((id >> 3) & 3)) * 256;   // XCD owns 4 m-tiles
  const int n0 = (id >> 5) * 128;

  f32x4 acc[4][4]; ACC_ZERO4(acc);
  gemm_256x128(xb, W, m0, n0, 16, smem, acc);

  if (z < 2) {
    store256x128_bf16(acc, bias, n0, (z == 0) ? q : k, m0, smem);
  } else {
    const int tid = threadIdx.x, lane = tid & 63, wave = tid >> 6;
    const int quad = lane >> 4, l16 = lane & 15;
    const int wr = (wave >> 1) << 6, wc = (wave & 1) << 6;
    u16* t = (u16*)smem;                     // transposed: t[n_local][m_local], 128 x 264
#pragma unroll
    for (int j = 0; j < 4; ++j) {
      const int nn = wc + j * 16 + l16;
      const float bj = bias[n0 + nn];
#pragma unroll
      for (int i = 0; i < 4; ++i) {
        const int mm = wr + i * 16 + quad * 4;
#pragma unroll
        for (int r = 0; r < 4; ++r)
          t[nn * 264 + mm + r] = f2bf(acc[i][j][r] + bj);
      }
    }
    __syncthreads();
    const int b = m0 >> 10, t0 = m0 & 1023;
#pragma unroll
    for (int it = 0; it < 8; ++it) {
      const int L = it * 512 + tid;          // 128 rows x 32 chunks of 8
      const int nn = L >> 5, cc = L & 31;
      *(uint4*)(vt + ((size_t)b << 20) + (size_t)(n0 + nn) * 1024 + t0 + cc * 8) =
          *(const uint4*)(t + nn * 264 + cc * 8);
    }
  }
}

// ---------- kernel 3: P' = exp(scale*QK^T), causal; 256x128 tiles ----------
// grid = 160: batch-aligned XCD mapping — b = bid&7 pins all 20 tiles of
// batch b to XCD b, whose 4MB L2 holds exactly Q(b)+K(b) (2MB+2MB).
__global__ __launch_bounds__(512, 2) void qk_exp256(
    const u16* __restrict__ q, const u16* __restrict__ k,
    u16* __restrict__ probs, float* __restrict__ rowsum)
{
  __shared__ char smem[147456];
  const int id = blockIdx.x;                 // 0..159
  const int b = id & 7;                      // batch -> XCD (L2 locality)
  const int t = id >> 3;                     // 0..19
  const int qi = (t < 2) ? 0 : (t < 6) ? 1 : (t < 12) ? 2 : 3;
  const int pre = (qi == 0) ? 0 : (qi == 1) ? 2 : (qi == 2) ? 6 : 12;
  const int kt = t - pre;
  const int m0 = qi * 256, n0 = kt * 128;
  const u16* A = q + ((size_t)b << 20);
  const u16* B = k + ((size_t)b << 20);

  f32x4 acc[4][4]; ACC_ZERO4(acc);
  gemm_256x128(A, B, m0, n0, 16, smem, acc);

  const int tid = threadIdx.x, lane = tid & 63, wave = tid >> 6;
  const int quad = lane >> 4, l16 = lane & 15;
  const int wr = (wave >> 1) << 6, wc = (wave & 1) << 6;

  float part[4][4];
#pragma unroll
  for (int i = 0; i < 4; ++i)
#pragma unroll
    for (int r = 0; r < 4; ++r) part[i][r] = 0.f;

  u16* tl = (u16*)smem;                      // 256 x 136 u16 repack
#pragma unroll
  for (int j = 0; j < 4; ++j) {
    const int nn = wc + j * 16 + l16;
#pragma unroll
    for (int i = 0; i < 4; ++i) {
      const int mm = wr + i * 16 + quad * 4;
#pragma unroll
      for (int r = 0; r < 4; ++r) {
        float e = __expf(acc[i][j][r] * 0.03125f);
        if ((n0 + nn) > (m0 + mm + r)) e = 0.f; // causal (no-op for full tiles)
        part[i][r] += e;
        tl[(mm + r) * 136 + nn] = f2bf(e);
      }
    }
  }
  float* rs = rowsum + b * 1024 + m0;
#pragma unroll
  for (int i = 0; i < 4; ++i)
#pragma unroll
    for (int r = 0; r < 4; ++r) {
      float v = part[i][r];
      v += __shfl_xor(v, 1); v += __shfl_xor(v, 2);
      v += __shfl_xor(v, 4); v += __shfl_xor(v, 8);
      if (l16 == 0) atomicAdd(rs + wr + i * 16 + quad * 4 + r, v);
    }
  __syncthreads();
  u16* C = probs + ((size_t)b << 20);
#pragma unroll
  for (int it = 0; it < 8; ++it) {
    const int L = it * 512 + tid;            // 4096 chunks of 8 u16
    const int mm = L >> 4, cc = L & 15;
    *(uint4*)(C + (size_t)(m0 + mm) * 1024 + n0 + cc * 8) =
        *(const uint4*)(tl + mm * 136 + cc * 8);
  }
}

// ---------- kernel 4: O = diag(1/l) P' V; 256x128 tiles, variable K ----------
// grid = 256 blocks exactly: b = id&7 (batch -> XCD, already L2-aligned)
__global__ __launch_bounds__(512, 2) void pv256(
    const u16* __restrict__ probs, const u16* __restrict__ vt,
    const float* __restrict__ rowsum, u16* __restrict__ o)
{
  __shared__ char smem[147456];
  const int id = blockIdx.x;                 // 0..255
  const int b = id & 7;
  const int u = id >> 3;                     // 0..31
  const int qi = 3 - (u & 3);                // big-K blocks first
  const int nb = u >> 2;                     // 0..7
  const int m0 = qi * 256, n0 = nb * 128;
  const int nt = (qi + 1) * 4;               // K = (qi+1)*256, BK=64
  const u16* A = probs + ((size_t)b << 20);
  const u16* B = vt + ((size_t)b << 20);

  f32x4 acc[4][4]; ACC_ZERO4(acc);
  gemm_256x128(A, B, m0, n0, nt, smem, acc);

  const int tid = threadIdx.x, lane = tid & 63, wave = tid >> 6;
  const int quad = lane >> 4, l16 = lane & 15;
  const int wr = (wave >> 1) << 6, wc = (wave & 1) << 6;
  const float* rs = rowsum + b * 1024 + m0;
  u16* tl = (u16*)smem;                      // 256 x 136 u16
#pragma unroll
  for (int i = 0; i < 4; ++i)
#pragma unroll
    for (int r = 0; r < 4; ++r) {
      const int mm = wr + i * 16 + quad * 4 + r;
      const float inv = 1.0f / rs[mm];
#pragma unroll
      for (int j = 0; j < 4; ++j)
        tl[mm * 136 + wc + j * 16 + l16] = f2bf(acc[i][j][r] * inv);
    }
  __syncthreads();
  u16* C = o + ((size_t)b << 20);
#pragma unroll
  for (int it = 0; it < 8; ++it) {
    const int L = it * 512 + tid;
    const int mm = L >> 4, cc = L & 15;
    *(uint4*)(C + (size_t)(m0 + mm) * 1024 + n0 + cc * 8) =
        *(const uint4*)(tl + mm * 136 + cc * 8);
  }
}

// ---------- kernel 5: out = O Wo^T + bo; fp32 epilogue ----------
__global__ __launch_bounds__(512, 2) void proj_o(
    const u16* __restrict__ ob, const u16* __restrict__ wob,
    const float* __restrict__ bo, float* __restrict__ out)
{
  __shared__ char smem[147456];
  const int id = blockIdx.x;                 // 0..255
  const int m0 = ((id & 7) * 4 + ((id >> 3) & 3)) * 256;
  const int n0 = (id >> 5) * 128;
  f32x4 acc[4][4]; ACC_ZERO4(acc);
  gemm_256x128(ob, wob, m0, n0, 16, smem, acc);

  const int tid = threadIdx.x, lane = tid & 63, wave = tid >> 6;
  const int quad = lane >> 4, l16 = lane & 15;
  const int wr = (wave >> 1) << 6, wc = (wave & 1) << 6;
  float* tf = (float*)smem;                  // 256 x 132 fp32
#pragma unroll
  for (int j = 0; j < 4; ++j) {
    const int nn = wc + j * 16 + l16;
    const float bj = bo[n0 + nn];
#pragma unroll
    for (int i = 0; i < 4; ++i)
#pragma unroll
      for (int r = 0; r < 4; ++r)
        tf[(wr + i * 16 + quad * 4 + r) * 132 + nn] = acc[i][j][r] + bj;
  }
  __syncthreads();
#pragma unroll
  for (int it = 0; it < 16; ++it) {
    const int L = it * 512 + tid;            // 256 rows x 32 float4
    const int mm = L >> 5, cc = L & 31;
    *(float4*)(out + (size_t)(m0 + mm) * 1024 + n0 + cc * 4) =
        *(const float4*)(tf + mm * 132 + cc * 4);
  }
}

// ---------- launch ----------
extern "C" void kernel_launch(void* const* d_in, const int* in_sizes, int n_in,
                              void* d_out, int out_size, void* d_ws, size_t ws_size,
                              hipStream_t stream) {
  const float* x  = (const float*)d_in[0];
  const float* wq = (const float*)d_in[1];
  const float* bq = (const float*)d_in[2];
  const float* wk = (const float*)d_in[3];
  const float* bk = (const float*)d_in[4];
  const float* wv = (const float*)d_in[5];
  const float* bv = (const float*)d_in[6];
  const float* wo = (const float*)d_in[7];
  const float* bo = (const float*)d_in[8];
  float* out = (float*)d_out;

  char* ws = (char*)d_ws;
  const size_t MB = 1u << 20;
  u16*  xb  = (u16*)(ws);            // 16 MB (x bf16; reused later as O bf16)
  u16*  wqb = (u16*)(ws + 16*MB);
  u16*  wkb = (u16*)(ws + 18*MB);
  u16*  wvb = (u16*)(ws + 20*MB);
  u16*  wob = (u16*)(ws + 22*MB);
  u16*  qb  = (u16*)(ws + 24*MB);
  u16*  kb  = (u16*)(ws + 40*MB);
  u16*  vtb = (u16*)(ws + 56*MB);    // V transposed per batch
  u16*  pr  = (u16*)(ws + 72*MB);    // bf16 unnormalized probs P'
  float* rsum = (float*)(ws + 88*MB);// 32 KB row sums

  cast_inputs<<<6144, 256, 0, stream>>>(x, wq, wk, wv, wo, xb, wqb, wkb, wvb, wob, rsum);
  proj_qkv<<<dim3(256, 3), 512, 0, stream>>>(xb, wqb, wkb, wvb, bq, bk, bv, qb, kb, vtb);
  qk_exp256<<<160, 512, 0, stream>>>(qb, kb, pr, rsum);
  pv256<<<256, 512, 0, stream>>>(pr, vtb, rsum, xb /* O reuses x region */);
  proj_o<<<256, 512, 0, stream>>>(xb, wob, bo, out);
}